// Round 3
// baseline (973.888 us; speedup 1.0000x reference)
//
#include <hip/hip_runtime.h>

#define SLEN  512
#define BATCH 256
#define NTAGS 128
#define NTHR  512   // j = tid>>2 (0..127), h = tid&3 (i-range split 4-ways within a quad)

// quad_perm DPP: each lane of a quad reads another lane of the same quad. Pure VALU.
__device__ __forceinline__ int dpp_qperm_b1(int x) {  // lane <- lane^1  [1,0,3,2]
    return __builtin_amdgcn_update_dpp(0, x, 0xB1, 0xF, 0xF, true);
}
__device__ __forceinline__ int dpp_qperm_4e(int x) {  // lane <- lane^2  [2,3,0,1]
    return __builtin_amdgcn_update_dpp(0, x, 0x4E, 0xF, 0xF, true);
}

__global__ __launch_bounds__(NTHR) void viterbi_kernel(
    const float* __restrict__ em,      // [S,B,T]
    const int*   __restrict__ mask,    // [S,B]
    const float* __restrict__ start_t, // [T]
    const float* __restrict__ end_t,   // [T]
    const float* __restrict__ trans,   // [T,T]
    float* __restrict__ out)           // [B*S] tags (as float), then [B] scores
{
    const int b   = blockIdx.x;
    const int tid = threadIdx.x;
    const int j   = tid >> 2;          // 0..127
    const int h   = tid & 3;           // 0..3
    const bool writer = (h == 0);
    const int hbase = h << 5;          // h*32

    // sc double-buffer, bank-staggered: group h stored at float offset h*40
    // (bank quads {0,8,16,24} -> the 4 broadcast b128 reads are conflict-free)
    __shared__ __align__(16) float scbuf[2][4 * 40];
    __shared__ float fin[NTAGS];
    __shared__ int   maskv[SLEN];
    __shared__ unsigned char hist[SLEN - 1][NTAGS];   // 65408 B
    __shared__ unsigned char exitc[8][NTAGS];         // backtrace chunk exits
    __shared__ unsigned char st_tags[8];              // chunk-top tags after stitch
    __shared__ unsigned char tagseq[SLEN];
    __shared__ float bestval_s;
    __shared__ int   bestj_s;

    // Transition column chunk in registers: trcol[k] = trans[hbase+k][j]
    float trcol[32];
#pragma unroll
    for (int k = 0; k < 32; ++k)
        trcol[k] = trans[(hbase + k) * NTAGS + j];

    for (int t = tid; t < SLEN; t += NTHR)
        maskv[t] = mask[t * BATCH + b];

    // score0 = start + emissions[0]; writer lanes carry sc[j] in a register too
    float scj = 0.f;
    if (writer) {
        scj = start_t[j] + em[(size_t)b * NTAGS + j];
        scbuf[0][j + (j >> 5) * 8] = scj;
    }
    __syncthreads();

    const float* emp = em + (size_t)BATCH * NTAGS + (size_t)b * NTAGS + j; // t=1
    float em_next = *emp;

    int p = 0;
    for (int t = 1; t < SLEN; ++t) {
        const float em_cur = em_next;
        if (t + 1 < SLEN) { emp += BATCH * NTAGS; em_next = *emp; }

        // Load this thread's 32 sc values (broadcast within 16-lane groups)
        float sv[32];
        {
            const float4* sp = (const float4*)&scbuf[p][h * 40];
#pragma unroll
            for (int r = 0; r < 8; ++r) {
                float4 q = sp[r];
                sv[4*r+0] = q.x; sv[4*r+1] = q.y; sv[4*r+2] = q.z; sv[4*r+3] = q.w;
            }
        }

        // Candidates c_k = fl(fl(sc[i]+tr[i][j]) + em) — exact ref associativity.
        // Level 0 fused: pairwise combine, strict > keeps first (lower-i) max.
        float bv[16]; int bi[16];
#pragma unroll
        for (int k = 0; k < 16; ++k) {
            float ca = (sv[2*k]     + trcol[2*k])     + em_cur;
            float cb = (sv[2*k + 1] + trcol[2*k + 1]) + em_cur;
            bool tk = cb > ca;
            bv[k] = tk ? cb : ca;
            bi[k] = tk ? (2*k + 1) : (2*k);
        }
        // Tree levels: combine ADJACENT pairs so every group stays a contiguous
        // index range with the left group strictly lower -> strict > is tie-exact.
#pragma unroll
        for (int w = 16; w > 1; w >>= 1) {
#pragma unroll
            for (int k = 0; k < (w >> 1); ++k) {
                bool tk = bv[2*k + 1] > bv[2*k];
                bv[k] = tk ? bv[2*k + 1] : bv[2*k];
                bi[k] = tk ? bi[2*k + 1] : bi[2*k];
            }
        }

        // Quad butterfly via DPP. From the h==0 lane's perspective the partner
        // always holds a HIGHER i-base, so strict > keeps the first max.
        float v = bv[0];
        int  gi = hbase + bi[0];
        {
            float vo = __int_as_float(dpp_qperm_b1(__float_as_int(v)));
            int   io = dpp_qperm_b1(gi);
            bool tk = vo > v;
            v = tk ? vo : v; gi = tk ? io : gi;
        }
        {
            float vo = __int_as_float(dpp_qperm_4e(__float_as_int(v)));
            int   io = dpp_qperm_4e(gi);
            bool tk = vo > v;
            v = tk ? vo : v; gi = tk ? io : gi;
        }

        if (writer) {
            hist[t - 1][j] = (unsigned char)gi;   // recorded unconditionally (ref does too)
            scj = maskv[t] ? v : scj;             // where(mask, next, old), register-carried
            scbuf[p ^ 1][j + (j >> 5) * 8] = scj;
        }
        __syncthreads();
        p ^= 1;
    }

    // final = sc + end_transitions
    if (tid < NTAGS) fin[tid] = scbuf[p][tid + (tid >> 5) * 8] + end_t[tid];
    __syncthreads();

    // first-occurrence argmax over 128 tags (wave 0)
    if (tid < 64) {
        float v  = fin[tid]; int bj = tid;
        float v1 = fin[tid + 64];
        if (v1 > v) { v = v1; bj = tid + 64; }
#pragma unroll
        for (int off = 32; off > 0; off >>= 1) {
            float ov = __shfl_xor(v, off, 64);
            int   oj = __shfl_xor(bj, off, 64);
            if (ov > v || (ov == v && oj < bj)) { v = ov; bj = oj; }
        }
        if (tid == 0) { bestval_s = v; bestj_s = bj; }
    }
    __syncthreads();

    // ---- Backtrace, chunked: tag[s] = maskv[s+1] ? hist[s][tag[s+1]] : tag[s+1]
    // Phase 1: 8 chunks x 128 speculative entry tags = 1024 chains (2 per thread)
    {
        const int k  = tid & 127;
        const int c0 = tid >> 7;       // 0..3
        const int c1 = c0 + 4;         // 4..7
        int tagA = k, tagB = k;
        for (int u = 63; u >= 0; --u) {
            const int sA = c0 * 64 + u;           // <= 255, always valid
            const int sB = c1 * 64 + u;           // == 511 only at (c1==7,u==63)
            if (sB <= SLEN - 2) {
                int pv = hist[sB][tagB];
                tagB = maskv[sB + 1] ? pv : tagB;
            }
            int pv = hist[sA][tagA];
            tagA = maskv[sA + 1] ? pv : tagA;
        }
        exitc[c0][k] = (unsigned char)tagA;
        exitc[c1][k] = (unsigned char)tagB;
    }
    __syncthreads();

    // Phase 2: stitch chunk boundaries (8 dependent LDS reads)
    if (tid == 0) {
        int tag = bestj_s;
        for (int c = 7; c >= 0; --c) {
            st_tags[c] = (unsigned char)tag;      // tag at top boundary of chunk c
            tag = exitc[c][tag];
        }
        out[BATCH * SLEN + b] = bestval_s;        // best_path_score
    }
    __syncthreads();

    // Phase 3: 8 parallel re-chases writing the actual tag sequence
    if (tid < 8) {
        const int c = tid;
        int tag = st_tags[c];
        if (c == 7) tagseq[SLEN - 1] = (unsigned char)tag;
        const int shi = (c == 7) ? (SLEN - 2) : (c * 64 + 63);
        for (int s = shi; s >= c * 64; --s) {
            int pv = hist[s][tag];
            tag = maskv[s + 1] ? pv : tag;
            tagseq[s] = (unsigned char)tag;
        }
    }
    __syncthreads();

    // Coalesced tag writeout as float: out0 is tags.T -> [B, S] row-major
    out[b * SLEN + tid] = (float)tagseq[tid];
}

extern "C" void kernel_launch(void* const* d_in, const int* in_sizes, int n_in,
                              void* d_out, int out_size, void* d_ws, size_t ws_size,
                              hipStream_t stream) {
    const float* em      = (const float*)d_in[0];
    const int*   mask    = (const int*)d_in[1];
    const float* start_t = (const float*)d_in[2];
    const float* end_t   = (const float*)d_in[3];
    const float* trans   = (const float*)d_in[4];
    float* out = (float*)d_out;

    viterbi_kernel<<<dim3(BATCH), dim3(NTHR), 0, stream>>>(
        em, mask, start_t, end_t, trans, out);
}

// Round 4
// 416.050 us; speedup vs baseline: 2.3408x; 2.3408x over previous
//
#include <hip/hip_runtime.h>

#define SLEN  512
#define BATCH 256
#define NTAGS 128
#define NTHR  512   // j = tid&127, h = tid>>7 : wave-uniform h, broadcast sc reads

// Value+index pair; vmax2(a,b) where b carries the HIGHER index:
// strict > keeps the first (lower-index) maximum -> np.argmax tie rule.
struct VI { float v; int i; };
__device__ __forceinline__ VI vmax2(VI a, VI b) { return (b.v > a.v) ? b : a; }

__global__ __launch_bounds__(NTHR) void viterbi_kernel(
    const float* __restrict__ em,      // [S,B,T]
    const int*   __restrict__ mask,    // [S,B]
    const float* __restrict__ start_t, // [T]
    const float* __restrict__ end_t,   // [T]
    const float* __restrict__ trans,   // [T,T]
    float* __restrict__ out)           // [B*S] tags (as float), then [B] scores
{
    const int b    = blockIdx.x;
    const int tid  = threadIdx.x;
    const int j    = tid & (NTAGS - 1);
    const int h    = tid >> 7;         // 0..3, uniform per wave
    const int base = h << 5;           // h*32

    __shared__ __align__(16) float sc[NTAGS];
    __shared__ float pmax[4][NTAGS];
    __shared__ int   pidx[4][NTAGS];
    __shared__ int   maskv[SLEN];
    __shared__ unsigned char hist[SLEN - 1][NTAGS];   // 65408 B
    __shared__ unsigned char exitc[8][NTAGS];
    __shared__ unsigned char st_tags[8];
    __shared__ unsigned char tagseq[SLEN];
    __shared__ float bestval_s;
    __shared__ int   bestj_s;

    // ---- 32 NAMED transition-column registers (no array -> no scratch) ----
    const float* trp = trans + (size_t)base * NTAGS + j;   // trans[base+k][j]
    const float t00 = trp[ 0*NTAGS], t01 = trp[ 1*NTAGS], t02 = trp[ 2*NTAGS], t03 = trp[ 3*NTAGS];
    const float t04 = trp[ 4*NTAGS], t05 = trp[ 5*NTAGS], t06 = trp[ 6*NTAGS], t07 = trp[ 7*NTAGS];
    const float t08 = trp[ 8*NTAGS], t09 = trp[ 9*NTAGS], t10 = trp[10*NTAGS], t11 = trp[11*NTAGS];
    const float t12 = trp[12*NTAGS], t13 = trp[13*NTAGS], t14 = trp[14*NTAGS], t15 = trp[15*NTAGS];
    const float t16 = trp[16*NTAGS], t17 = trp[17*NTAGS], t18 = trp[18*NTAGS], t19 = trp[19*NTAGS];
    const float t20 = trp[20*NTAGS], t21 = trp[21*NTAGS], t22 = trp[22*NTAGS], t23 = trp[23*NTAGS];
    const float t24 = trp[24*NTAGS], t25 = trp[25*NTAGS], t26 = trp[26*NTAGS], t27 = trp[27*NTAGS];
    const float t28 = trp[28*NTAGS], t29 = trp[29*NTAGS], t30 = trp[30*NTAGS], t31 = trp[31*NTAGS];

    for (int t = tid; t < SLEN; t += NTHR)
        maskv[t] = mask[t * BATCH + b];

    if (tid < NTAGS)
        sc[j] = start_t[j] + em[(size_t)b * NTAGS + j];   // exact ref associativity
    __syncthreads();

    const float* emp = em + (size_t)BATCH * NTAGS + (size_t)b * NTAGS + j; // t=1
    float em_next = *emp;

    for (int t = 1; t < SLEN; ++t) {
        const float em_cur = em_next;
        if (t + 1 < SLEN) { emp += BATCH * NTAGS; em_next = *emp; }

        // Broadcast sc reads: wave-uniform address -> conflict-free
        const float4* sq = (const float4*)&sc[base];
        const float4 q0 = sq[0], q1 = sq[1], q2 = sq[2], q3 = sq[3];
        const float4 q4 = sq[4], q5 = sq[5], q6 = sq[6], q7 = sq[7];

        // 32 candidates: c_k = fl(fl(sc[base+k] + trans[base+k][j]) + em) — exact ref order
        const float c00 = (q0.x + t00) + em_cur, c01 = (q0.y + t01) + em_cur;
        const float c02 = (q0.z + t02) + em_cur, c03 = (q0.w + t03) + em_cur;
        const float c04 = (q1.x + t04) + em_cur, c05 = (q1.y + t05) + em_cur;
        const float c06 = (q1.z + t06) + em_cur, c07 = (q1.w + t07) + em_cur;
        const float c08 = (q2.x + t08) + em_cur, c09 = (q2.y + t09) + em_cur;
        const float c10 = (q2.z + t10) + em_cur, c11 = (q2.w + t11) + em_cur;
        const float c12 = (q3.x + t12) + em_cur, c13 = (q3.y + t13) + em_cur;
        const float c14 = (q3.z + t14) + em_cur, c15 = (q3.w + t15) + em_cur;
        const float c16 = (q4.x + t16) + em_cur, c17 = (q4.y + t17) + em_cur;
        const float c18 = (q4.z + t18) + em_cur, c19 = (q4.w + t19) + em_cur;
        const float c20 = (q5.x + t20) + em_cur, c21 = (q5.y + t21) + em_cur;
        const float c22 = (q5.z + t22) + em_cur, c23 = (q5.w + t23) + em_cur;
        const float c24 = (q6.x + t24) + em_cur, c25 = (q6.y + t25) + em_cur;
        const float c26 = (q6.z + t26) + em_cur, c27 = (q6.w + t27) + em_cur;
        const float c28 = (q7.x + t28) + em_cur, c29 = (q7.y + t29) + em_cur;
        const float c30 = (q7.z + t30) + em_cur, c31 = (q7.w + t31) + em_cur;

        // Adjacent-pair tree: left operand always has the lower index range,
        // strict > at every level == first-occurrence argmax. All named vars.
        const VI m00 = vmax2(VI{c00, 0}, VI{c01, 1}),  m01 = vmax2(VI{c02, 2}, VI{c03, 3});
        const VI m02 = vmax2(VI{c04, 4}, VI{c05, 5}),  m03 = vmax2(VI{c06, 6}, VI{c07, 7});
        const VI m04 = vmax2(VI{c08, 8}, VI{c09, 9}),  m05 = vmax2(VI{c10,10}, VI{c11,11});
        const VI m06 = vmax2(VI{c12,12}, VI{c13,13}),  m07 = vmax2(VI{c14,14}, VI{c15,15});
        const VI m08 = vmax2(VI{c16,16}, VI{c17,17}),  m09 = vmax2(VI{c18,18}, VI{c19,19});
        const VI m10 = vmax2(VI{c20,20}, VI{c21,21}),  m11 = vmax2(VI{c22,22}, VI{c23,23});
        const VI m12 = vmax2(VI{c24,24}, VI{c25,25}),  m13 = vmax2(VI{c26,26}, VI{c27,27});
        const VI m14 = vmax2(VI{c28,28}, VI{c29,29}),  m15 = vmax2(VI{c30,30}, VI{c31,31});

        const VI n0 = vmax2(m00, m01), n1 = vmax2(m02, m03);
        const VI n2 = vmax2(m04, m05), n3 = vmax2(m06, m07);
        const VI n4 = vmax2(m08, m09), n5 = vmax2(m10, m11);
        const VI n6 = vmax2(m12, m13), n7 = vmax2(m14, m15);

        const VI o0 = vmax2(n0, n1), o1 = vmax2(n2, n3);
        const VI o2 = vmax2(n4, n5), o3 = vmax2(n6, n7);

        const VI p0 = vmax2(o0, o1), p1 = vmax2(o2, o3);
        const VI r  = vmax2(p0, p1);

        pmax[h][j] = r.v;
        pidx[h][j] = base + r.i;
        __syncthreads();

        if (tid < NTAGS) {   // waves 0-1: combine 4 partials ascending h
            float bv = pmax[0][j]; int bi = pidx[0][j];
            float v1 = pmax[1][j]; int i1 = pidx[1][j];
            if (v1 > bv) { bv = v1; bi = i1; }
            float v2 = pmax[2][j]; int i2 = pidx[2][j];
            if (v2 > bv) { bv = v2; bi = i2; }
            float v3 = pmax[3][j]; int i3 = pidx[3][j];
            if (v3 > bv) { bv = v3; bi = i3; }
            hist[t - 1][j] = (unsigned char)bi;   // recorded unconditionally (ref does too)
            if (maskv[t]) sc[j] = bv;             // where(mask, next, old)
        }
        __syncthreads();
    }

    // final = sc + end_transitions; first-occurrence argmax over 128
    if (tid < NTAGS) sc[j] = sc[j] + end_t[j];
    __syncthreads();

    if (tid < 64) {
        float v  = sc[tid]; int bj = tid;
        float v1 = sc[tid + 64];
        if (v1 > v) { v = v1; bj = tid + 64; }
#pragma unroll
        for (int off = 32; off > 0; off >>= 1) {
            float ov = __shfl_xor(v, off, 64);
            int   oj = __shfl_xor(bj, off, 64);
            if (ov > v || (ov == v && oj < bj)) { v = ov; bj = oj; }
        }
        if (tid == 0) { bestval_s = v; bestj_s = bj; }
    }
    __syncthreads();

    // ---- Chunked parallel backtrace (proven bit-exact in round 3) ----
    // Phase 1: 8 chunks x 128 speculative entry tags (2 chains/thread, ILP)
    {
        const int k  = tid & 127;
        const int c0 = tid >> 7;       // 0..3
        const int c1 = c0 + 4;         // 4..7
        int tagA = k, tagB = k;
        for (int u = 63; u >= 0; --u) {
            const int sA = c0 * 64 + u;
            const int sB = c1 * 64 + u;
            if (sB <= SLEN - 2) {
                int pv = hist[sB][tagB];
                tagB = maskv[sB + 1] ? pv : tagB;
            }
            int pv = hist[sA][tagA];
            tagA = maskv[sA + 1] ? pv : tagA;
        }
        exitc[c0][k] = (unsigned char)tagA;
        exitc[c1][k] = (unsigned char)tagB;
    }
    __syncthreads();

    // Phase 2: stitch chunk boundaries
    if (tid == 0) {
        int tag = bestj_s;
        for (int c = 7; c >= 0; --c) {
            st_tags[c] = (unsigned char)tag;
            tag = exitc[c][tag];
        }
        out[BATCH * SLEN + b] = bestval_s;        // best_path_score
    }
    __syncthreads();

    // Phase 3: 8 parallel re-chases writing the tag sequence
    if (tid < 8) {
        const int c = tid;
        int tag = st_tags[c];
        if (c == 7) tagseq[SLEN - 1] = (unsigned char)tag;
        const int shi = (c == 7) ? (SLEN - 2) : (c * 64 + 63);
        for (int s = shi; s >= c * 64; --s) {
            int pv = hist[s][tag];
            tag = maskv[s + 1] ? pv : tag;
            tagseq[s] = (unsigned char)tag;
        }
    }
    __syncthreads();

    // Coalesced tag writeout as float: out0 is tags.T -> [B, S] row-major
    out[b * SLEN + tid] = (float)tagseq[tid];
}

extern "C" void kernel_launch(void* const* d_in, const int* in_sizes, int n_in,
                              void* d_out, int out_size, void* d_ws, size_t ws_size,
                              hipStream_t stream) {
    const float* em      = (const float*)d_in[0];
    const int*   mask    = (const int*)d_in[1];
    const float* start_t = (const float*)d_in[2];
    const float* end_t   = (const float*)d_in[3];
    const float* trans   = (const float*)d_in[4];
    float* out = (float*)d_out;

    viterbi_kernel<<<dim3(BATCH), dim3(NTHR), 0, stream>>>(
        em, mask, start_t, end_t, trans, out);
}

// Round 5
// 405.719 us; speedup vs baseline: 2.4004x; 1.0255x over previous
//
#include <hip/hip_runtime.h>

#define SLEN  512
#define BATCH 256
#define NTAGS 128
#define NTHR  512   // j = tid>>2 (0..127), h = tid&3 (quad lane) -> 1 barrier/step

// quad_perm DPP: each lane of a quad reads another lane of the same quad. Pure VALU.
__device__ __forceinline__ int dpp_qperm_b1(int x) {  // lane <- lane^1  [1,0,3,2]
    return __builtin_amdgcn_update_dpp(0, x, 0xB1, 0xF, 0xF, true);
}
__device__ __forceinline__ int dpp_qperm_4e(int x) {  // lane <- lane^2  [2,3,0,1]
    return __builtin_amdgcn_update_dpp(0, x, 0x4E, 0xF, 0xF, true);
}

// Value+index pair; b must carry the HIGHER index range:
// strict > keeps the first (lower-index) maximum -> np.argmax tie rule.
struct VI { float v; int i; };
__device__ __forceinline__ VI vmax2(VI a, VI b) { return (b.v > a.v) ? b : a; }

__global__ __launch_bounds__(NTHR, 2) void viterbi_kernel(
    const float* __restrict__ em,      // [S,B,T]
    const int*   __restrict__ mask,    // [S,B]
    const float* __restrict__ start_t, // [T]
    const float* __restrict__ end_t,   // [T]
    const float* __restrict__ trans,   // [T,T]
    float* __restrict__ out)           // [B*S] tags (as float), then [B] scores
{
    const int b    = blockIdx.x;
    const int tid  = threadIdx.x;
    const int j    = tid >> 2;         // 0..127
    const int h    = tid & 3;          // 0..3  (quad lane)
    const int base = h << 5;           // h*32
    const bool writer = (h == 0);
    const int jslot = j + (j >> 5) * 8;   // staggered slot: chunk h at float offset h*40

    // sc double-buffer, bank-staggered (chunk h -> banks {8h..8h+7} per read round)
    __shared__ __align__(16) float scbuf[2][4 * 40];
    __shared__ float fin[NTAGS];
    __shared__ int   maskv[SLEN];
    __shared__ unsigned char hist[SLEN - 1][NTAGS];   // 65408 B
    __shared__ unsigned char exitc[8][NTAGS];
    __shared__ unsigned char st_tags[8];
    __shared__ unsigned char tagseq[SLEN];
    __shared__ float bestval_s;
    __shared__ int   bestj_s;

    // ---- 32 NAMED transition-column registers: trans[base+k][j] ----
    const float* trp = trans + (size_t)base * NTAGS + j;
    const float t00 = trp[ 0*NTAGS], t01 = trp[ 1*NTAGS], t02 = trp[ 2*NTAGS], t03 = trp[ 3*NTAGS];
    const float t04 = trp[ 4*NTAGS], t05 = trp[ 5*NTAGS], t06 = trp[ 6*NTAGS], t07 = trp[ 7*NTAGS];
    const float t08 = trp[ 8*NTAGS], t09 = trp[ 9*NTAGS], t10 = trp[10*NTAGS], t11 = trp[11*NTAGS];
    const float t12 = trp[12*NTAGS], t13 = trp[13*NTAGS], t14 = trp[14*NTAGS], t15 = trp[15*NTAGS];
    const float t16 = trp[16*NTAGS], t17 = trp[17*NTAGS], t18 = trp[18*NTAGS], t19 = trp[19*NTAGS];
    const float t20 = trp[20*NTAGS], t21 = trp[21*NTAGS], t22 = trp[22*NTAGS], t23 = trp[23*NTAGS];
    const float t24 = trp[24*NTAGS], t25 = trp[25*NTAGS], t26 = trp[26*NTAGS], t27 = trp[27*NTAGS];
    const float t28 = trp[28*NTAGS], t29 = trp[29*NTAGS], t30 = trp[30*NTAGS], t31 = trp[31*NTAGS];

    for (int t = tid; t < SLEN; t += NTHR)
        maskv[t] = mask[t * BATCH + b];

    // score0 = start + emissions[0]; writer lanes also carry sc[j] in a register
    float scj = 0.f;
    if (writer) {
        scj = start_t[j] + em[(size_t)b * NTAGS + j];   // exact ref associativity
        scbuf[0][jslot] = scj;
    }
    __syncthreads();

    const float* emp = em + (size_t)BATCH * NTAGS + (size_t)b * NTAGS + j; // t=1
    float em_next = *emp;

    int p = 0;
    for (int t = 1; t < SLEN; ++t) {
        const float em_cur = em_next;
        if (t + 1 < SLEN) { emp += BATCH * NTAGS; em_next = *emp; }

        // 8 named float4 broadcast reads of this thread's sc chunk
        const float4* sq = (const float4*)&scbuf[p][h * 40];
        const float4 q0 = sq[0], q1 = sq[1], q2 = sq[2], q3 = sq[3];
        const float4 q4 = sq[4], q5 = sq[5], q6 = sq[6], q7 = sq[7];

        // 32 candidates: c_k = fl(fl(sc[base+k] + trans[base+k][j]) + em) — exact ref order
        const float c00 = (q0.x + t00) + em_cur, c01 = (q0.y + t01) + em_cur;
        const float c02 = (q0.z + t02) + em_cur, c03 = (q0.w + t03) + em_cur;
        const float c04 = (q1.x + t04) + em_cur, c05 = (q1.y + t05) + em_cur;
        const float c06 = (q1.z + t06) + em_cur, c07 = (q1.w + t07) + em_cur;
        const float c08 = (q2.x + t08) + em_cur, c09 = (q2.y + t09) + em_cur;
        const float c10 = (q2.z + t10) + em_cur, c11 = (q2.w + t11) + em_cur;
        const float c12 = (q3.x + t12) + em_cur, c13 = (q3.y + t13) + em_cur;
        const float c14 = (q3.z + t14) + em_cur, c15 = (q3.w + t15) + em_cur;
        const float c16 = (q4.x + t16) + em_cur, c17 = (q4.y + t17) + em_cur;
        const float c18 = (q4.z + t18) + em_cur, c19 = (q4.w + t19) + em_cur;
        const float c20 = (q5.x + t20) + em_cur, c21 = (q5.y + t21) + em_cur;
        const float c22 = (q5.z + t22) + em_cur, c23 = (q5.w + t23) + em_cur;
        const float c24 = (q6.x + t24) + em_cur, c25 = (q6.y + t25) + em_cur;
        const float c26 = (q6.z + t26) + em_cur, c27 = (q6.w + t27) + em_cur;
        const float c28 = (q7.x + t28) + em_cur, c29 = (q7.y + t29) + em_cur;
        const float c30 = (q7.z + t30) + em_cur, c31 = (q7.w + t31) + em_cur;

        // Adjacent-pair tree, all named: strict > at every level == first-occurrence argmax
        const VI m00 = vmax2(VI{c00, 0}, VI{c01, 1}),  m01 = vmax2(VI{c02, 2}, VI{c03, 3});
        const VI m02 = vmax2(VI{c04, 4}, VI{c05, 5}),  m03 = vmax2(VI{c06, 6}, VI{c07, 7});
        const VI m04 = vmax2(VI{c08, 8}, VI{c09, 9}),  m05 = vmax2(VI{c10,10}, VI{c11,11});
        const VI m06 = vmax2(VI{c12,12}, VI{c13,13}),  m07 = vmax2(VI{c14,14}, VI{c15,15});
        const VI m08 = vmax2(VI{c16,16}, VI{c17,17}),  m09 = vmax2(VI{c18,18}, VI{c19,19});
        const VI m10 = vmax2(VI{c20,20}, VI{c21,21}),  m11 = vmax2(VI{c22,22}, VI{c23,23});
        const VI m12 = vmax2(VI{c24,24}, VI{c25,25}),  m13 = vmax2(VI{c26,26}, VI{c27,27});
        const VI m14 = vmax2(VI{c28,28}, VI{c29,29}),  m15 = vmax2(VI{c30,30}, VI{c31,31});

        const VI n0 = vmax2(m00, m01), n1 = vmax2(m02, m03);
        const VI n2 = vmax2(m04, m05), n3 = vmax2(m06, m07);
        const VI n4 = vmax2(m08, m09), n5 = vmax2(m10, m11);
        const VI n6 = vmax2(m12, m13), n7 = vmax2(m14, m15);

        const VI o0 = vmax2(n0, n1), o1 = vmax2(n2, n3);
        const VI o2 = vmax2(n4, n5), o3 = vmax2(n6, n7);

        const VI p0 = vmax2(o0, o1), p1 = vmax2(o2, o3);
        const VI r  = vmax2(p0, p1);

        // Quad butterfly via DPP: from lane h==0's view the partner always holds
        // a HIGHER i-base, so strict > keeps the first max (only h==0 is consumed).
        float v  = r.v;
        int   gi = base + r.i;
        {
            float vo = __int_as_float(dpp_qperm_b1(__float_as_int(v)));
            int   io = dpp_qperm_b1(gi);
            if (vo > v) { v = vo; gi = io; }
        }
        {
            float vo = __int_as_float(dpp_qperm_4e(__float_as_int(v)));
            int   io = dpp_qperm_4e(gi);
            if (vo > v) { v = vo; gi = io; }
        }

        if (writer) {
            hist[t - 1][j] = (unsigned char)gi;   // recorded unconditionally (ref does too)
            scj = maskv[t] ? v : scj;             // where(mask, next, old), register-carried
            scbuf[p ^ 1][jslot] = scj;
        }
        __syncthreads();                           // ONE barrier per step
        p ^= 1;
    }

    // final = sc + end_transitions, straight from writer registers
    if (writer) fin[j] = scj + end_t[j];
    __syncthreads();

    // first-occurrence argmax over 128 tags (wave 0)
    if (tid < 64) {
        float v  = fin[tid]; int bj = tid;
        float v1 = fin[tid + 64];
        if (v1 > v) { v = v1; bj = tid + 64; }
#pragma unroll
        for (int off = 32; off > 0; off >>= 1) {
            float ov = __shfl_xor(v, off, 64);
            int   oj = __shfl_xor(bj, off, 64);
            if (ov > v || (ov == v && oj < bj)) { v = ov; bj = oj; }
        }
        if (tid == 0) { bestval_s = v; bestj_s = bj; }
    }
    __syncthreads();

    // ---- Chunked parallel backtrace (proven bit-exact rounds 3-4) ----
    {
        const int k  = tid & 127;
        const int c0 = tid >> 7;       // 0..3
        const int c1 = c0 + 4;         // 4..7
        int tagA = k, tagB = k;
        for (int u = 63; u >= 0; --u) {
            const int sA = c0 * 64 + u;
            const int sB = c1 * 64 + u;
            if (sB <= SLEN - 2) {
                int pv = hist[sB][tagB];
                tagB = maskv[sB + 1] ? pv : tagB;
            }
            int pv = hist[sA][tagA];
            tagA = maskv[sA + 1] ? pv : tagA;
        }
        exitc[c0][k] = (unsigned char)tagA;
        exitc[c1][k] = (unsigned char)tagB;
    }
    __syncthreads();

    if (tid == 0) {
        int tag = bestj_s;
        for (int c = 7; c >= 0; --c) {
            st_tags[c] = (unsigned char)tag;
            tag = exitc[c][tag];
        }
        out[BATCH * SLEN + b] = bestval_s;        // best_path_score
    }
    __syncthreads();

    if (tid < 8) {
        const int c = tid;
        int tag = st_tags[c];
        if (c == 7) tagseq[SLEN - 1] = (unsigned char)tag;
        const int shi = (c == 7) ? (SLEN - 2) : (c * 64 + 63);
        for (int s = shi; s >= c * 64; --s) {
            int pv = hist[s][tag];
            tag = maskv[s + 1] ? pv : tag;
            tagseq[s] = (unsigned char)tag;
        }
    }
    __syncthreads();

    // Coalesced tag writeout as float: out0 is tags.T -> [B, S] row-major
    out[b * SLEN + tid] = (float)tagseq[tid];
}

extern "C" void kernel_launch(void* const* d_in, const int* in_sizes, int n_in,
                              void* d_out, int out_size, void* d_ws, size_t ws_size,
                              hipStream_t stream) {
    const float* em      = (const float*)d_in[0];
    const int*   mask    = (const int*)d_in[1];
    const float* start_t = (const float*)d_in[2];
    const float* end_t   = (const float*)d_in[3];
    const float* trans   = (const float*)d_in[4];
    float* out = (float*)d_out;

    viterbi_kernel<<<dim3(BATCH), dim3(NTHR), 0, stream>>>(
        em, mask, start_t, end_t, trans, out);
}